// Round 2
// baseline (99.052 us; speedup 1.0000x reference)
//
#include <hip/hip_runtime.h>
#include <math.h>

// MS_QCR: the 5-qubit circuit's expectation is exactly multilinear in
// (1, cos f_w, sin f_w) per input wire {0,1,3,4} (wire 2 angle fixed at 0):
//   out = readout_b + sum_{ijkl} T[i][j][k][l] * v0[i] v1[j] v3[k] v4[l]
// Kernel A (1 block): evaluates the verified statevector sim at the 81 sample
// tuples a in {0, 2pi/3, 4pi/3}^4 and applies M^{-1} per axis to get T (exact
// trigonometric interpolation). Kernel B (per-row): tiny conv nets -> features
// -> 81-term contraction. Final-layer ZZ phases are dropped (|amp|^2 invariant).

__global__ __launch_bounds__(128) void qcr_setup(
    const float* __restrict__ rw, const float* __restrict__ readout_w,
    const float* __restrict__ readout_b, float* __restrict__ T_out)
{
    __shared__ float s_rxc[15], s_rxs[15], s_ryc[15], s_rys[15];
    __shared__ float s_zzc[64], s_zzs[64], s_coef[32];
    __shared__ float s_e[81], s_g[81];

    const int tid = threadIdx.x;

    // ---- weight-derived gate tables ----
    if (tid < 15) {
        const int l = tid / 5, i = tid % 5;
        const float tx = rw[l*25 + i*5 + 0] * 0.5f;
        const float ty = rw[l*25 + i*5 + 1] * 0.5f;
        s_rxc[tid] = cosf(tx); s_rxs[tid] = sinf(tx);
        s_ryc[tid] = cosf(ty); s_rys[tid] = sinf(ty);
    }
    if (tid >= 16 && tid < 80) {            // ZZ phases, layers 0,1 only
        const int e = tid - 16;
        const int l = e >> 5, bi = e & 31;
        float ang = 0.f;
        for (int i = 0; i < 5; ++i) {
            const float si = ((bi >> (4 - i)) & 1) ? -1.f : 1.f;
            for (int j = i + 1; j < 5; ++j) {
                const float sj = ((bi >> (4 - j)) & 1) ? -1.f : 1.f;
                ang += rw[l*25 + i*5 + j] * si * sj;
            }
        }
        ang *= -0.5f;
        s_zzc[e] = cosf(ang); s_zzs[e] = sinf(ang);
    }
    if (tid >= 80 && tid < 112) {           // readout-weighted Z coefficient
        const int bi = tid - 80;
        float c = 0.f;
        for (int w = 0; w < 5; ++w) {
            const float sw = ((bi >> (4 - w)) & 1) ? -1.f : 1.f;
            c += readout_w[w] * sw;
        }
        s_coef[bi] = c;
    }
    __syncthreads();

    // ---- evaluate sim at the 81 sample tuples ----
    if (tid < 81) {
        const int d4 = tid % 3, d3 = (tid / 3) % 3, d1 = (tid / 9) % 3, d0 = tid / 27;
        // half-angle cos/sin of samples {0, 2pi/3, 4pi/3}
        const float SH = 0.8660254037844386f;
        const float p0c = d0==0 ? 1.f : (d0==1 ? 0.5f : -0.5f), p0s = d0==0 ? 0.f : SH;
        const float p1c = d1==0 ? 1.f : (d1==1 ? 0.5f : -0.5f), p1s = d1==0 ? 0.f : SH;
        const float p3c = d3==0 ? 1.f : (d3==1 ? 0.5f : -0.5f), p3s = d3==0 ? 0.f : SH;
        const float p4c = d4==0 ? 1.f : (d4==1 ? 0.5f : -0.5f), p4s = d4==0 ? 0.f : SH;

        float ar[32], ai[32];
        #pragma unroll
        for (int idx = 0; idx < 32; ++idx) {
            float v = 0.f;
            if (!((idx >> 2) & 1)) {        // wire 2 angle = 0 -> sin = 0
                v = ((idx >> 4) & 1 ? p0s : p0c)
                  * ((idx >> 3) & 1 ? p1s : p1c)
                  * ((idx >> 1) & 1 ? p3s : p3c)
                  * ((idx      ) & 1 ? p4s : p4c);
            }
            ar[idx] = v; ai[idx] = 0.f;
        }

        for (int l = 0; l < 3; ++l) {
            #pragma unroll
            for (int qb = 0; qb < 5; ++qb) {
                const float rc = s_rxc[l*5 + qb], rs = s_rxs[l*5 + qb];
                const float yc = s_ryc[l*5 + qb], ys = s_rys[l*5 + qb];
                const int str = 1 << (4 - qb);
                #pragma unroll
                for (int g = 0; g < 16; ++g) {
                    const int i0 = ((g & ~(str - 1)) << 1) | (g & (str - 1));
                    const int i1 = i0 | str;
                    const float a0r = ar[i0], a0i = ai[i0];
                    const float a1r = ar[i1], a1i = ai[i1];
                    const float n0r =  rc*a0r + rs*a1i;     // RX
                    const float n0i =  rc*a0i - rs*a1r;
                    const float n1r =  rs*a0i + rc*a1r;
                    const float n1i = -rs*a0r + rc*a1i;
                    ar[i0] = yc*n0r - ys*n1r;               // RY
                    ai[i0] = yc*n0i - ys*n1i;
                    ar[i1] = ys*n0r + yc*n1r;
                    ai[i1] = ys*n0i + yc*n1i;
                }
            }
            if (l < 2) {                    // final-layer ZZ phase is a no-op on probs
                #pragma unroll
                for (int idx = 0; idx < 32; ++idx) {
                    const float pc = s_zzc[l*32 + idx], ps = s_zzs[l*32 + idx];
                    const float r = ar[idx]*pc - ai[idx]*ps;
                    ai[idx]       = ar[idx]*ps + ai[idx]*pc;
                    ar[idx]       = r;
                }
            }
        }

        float acc = readout_b[0];
        #pragma unroll
        for (int idx = 0; idx < 32; ++idx)
            acc += (ar[idx]*ar[idx] + ai[idx]*ai[idx]) * s_coef[idx];
        s_e[tid] = acc;
    }
    __syncthreads();

    // ---- apply M^{-1} along each axis (sample index -> basis index) ----
    // M^{-1} = [[1/3,1/3,1/3],[2/3,-1/3,-1/3],[0,1/sqrt3,-1/sqrt3]]
    #define QCR_PASS(SRC, DST, ST)                                                        \
        if (tid < 81) {                                                                   \
            const int ii = (tid / ST) % 3;                                                \
            const int base = tid - ii * ST;                                               \
            const float a0 = ii==0 ? (1.f/3.f) : (ii==1 ? (2.f/3.f) : 0.f);               \
            const float a1 = ii==0 ? (1.f/3.f) : (ii==1 ? (-1.f/3.f) :  0.57735026918962576f); \
            const float a2 = ii==0 ? (1.f/3.f) : (ii==1 ? (-1.f/3.f) : -0.57735026918962576f); \
            DST[tid] = a0*SRC[base] + a1*SRC[base+ST] + a2*SRC[base+2*ST];                \
        }                                                                                 \
        __syncthreads();

    QCR_PASS(s_e, s_g, 1)    // wire-4 axis
    QCR_PASS(s_g, s_e, 3)    // wire-3 axis
    QCR_PASS(s_e, s_g, 9)    // wire-1 axis
    QCR_PASS(s_g, s_e, 27)   // wire-0 axis
    #undef QCR_PASS

    if (tid < 81) T_out[tid] = s_e[tid];
}

__global__ __launch_bounds__(256) void qcr_rows(
    const float* __restrict__ x_short, const float* __restrict__ x_long,
    const float* __restrict__ conv_s_w, const float* __restrict__ conv_s_b,
    const float* __restrict__ lin_s_w,  const float* __restrict__ lin_s_b,
    const float* __restrict__ conv_l_w, const float* __restrict__ conv_l_b,
    const float* __restrict__ lin_l_w,  const float* __restrict__ lin_l_b,
    const float* __restrict__ T_in, float* __restrict__ out, int nb)
{
    __shared__ float sT[81];
    if (threadIdx.x < 81) sT[threadIdx.x] = T_in[threadIdx.x];
    __syncthreads();

    const int b = blockIdx.x * 256 + threadIdx.x;
    if (b >= nb) return;

    // ---------------- classical: short branch ----------------
    float xs[5];
    #pragma unroll
    for (int p = 0; p < 5; ++p) xs[p] = x_short[b*5 + p];

    float f0 = lin_s_b[0], f1 = lin_s_b[1];
    #pragma unroll
    for (int c = 0; c < 4; ++c) {
        #pragma unroll
        for (int p = 0; p < 5; ++p) {
            float h = conv_s_b[c];
            #pragma unroll
            for (int k = 0; k < 3; ++k) {
                const int q = p - 1 + k;             // pad (1,1)
                if (q >= 0 && q < 5) h += conv_s_w[c*3 + k] * xs[q];
            }
            h = fmaxf(h, 0.f);
            f0 += lin_s_w[      c*5 + p] * h;
            f1 += lin_s_w[20 + c*5 + p] * h;
        }
    }

    // ---------------- classical: long branch ----------------
    float xl[20];
    #pragma unroll
    for (int p = 0; p < 20; ++p) xl[p] = x_long[b*20 + p];

    float g0 = lin_l_b[0], g1 = lin_l_b[1];
    #pragma unroll
    for (int c = 0; c < 4; ++c) {
        #pragma unroll
        for (int q = 0; q < 10; ++q) {
            float hm = 0.f;                          // relu(max(a,b)) = max(max(a,b),0)
            #pragma unroll
            for (int t = 0; t < 2; ++t) {
                const int p = 2*q + t;
                float h = conv_l_b[c];
                #pragma unroll
                for (int k = 0; k < 5; ++k) {
                    const int u = p - 2 + k;         // pad (2,2)
                    if (u >= 0 && u < 20) h += conv_l_w[c*5 + k] * xl[u];
                }
                hm = fmaxf(hm, h);
            }
            g0 += lin_l_w[      c*10 + q] * hm;
            g1 += lin_l_w[40 + c*10 + q] * hm;
        }
    }

    // ---------------- 81-term multilinear contraction ----------------
    const float c0 = __cosf(f0), sn0 = __sinf(f0);
    const float c1 = __cosf(f1), sn1 = __sinf(f1);
    const float c3 = __cosf(g0), sn3 = __sinf(g0);
    const float c4 = __cosf(g1), sn4 = __sinf(g1);

    float yi[3];
    #pragma unroll
    for (int i = 0; i < 3; ++i) {
        float xj[3];
        #pragma unroll
        for (int j = 0; j < 3; ++j) {
            float wk[3];
            #pragma unroll
            for (int k = 0; k < 3; ++k) {
                const int o = ((i*3 + j)*3 + k)*3;
                wk[k] = fmaf(sT[o+2], sn4, fmaf(sT[o+1], c4, sT[o]));
            }
            xj[j] = fmaf(wk[2], sn3, fmaf(wk[1], c3, wk[0]));
        }
        yi[i] = fmaf(xj[2], sn1, fmaf(xj[1], c1, xj[0]));
    }
    out[b] = fmaf(yi[2], sn0, fmaf(yi[1], c0, yi[0]));
}

extern "C" void kernel_launch(void* const* d_in, const int* in_sizes, int n_in,
                              void* d_out, int out_size, void* d_ws, size_t ws_size,
                              hipStream_t stream) {
    const float* x_short    = (const float*)d_in[0];
    const float* x_long     = (const float*)d_in[1];
    const float* conv_s_w   = (const float*)d_in[2];
    const float* conv_s_b   = (const float*)d_in[3];
    const float* lin_s_w    = (const float*)d_in[4];
    const float* lin_s_b    = (const float*)d_in[5];
    const float* conv_l_w   = (const float*)d_in[6];
    const float* conv_l_b   = (const float*)d_in[7];
    const float* lin_l_w    = (const float*)d_in[8];
    const float* lin_l_b    = (const float*)d_in[9];
    const float* rw         = (const float*)d_in[10];
    const float* readout_w  = (const float*)d_in[11];
    const float* readout_b  = (const float*)d_in[12];
    float* out = (float*)d_out;
    float* T   = (float*)d_ws;                // 81 floats of scratch

    const int nb = in_sizes[0] / 5;

    hipLaunchKernelGGL(qcr_setup, dim3(1), dim3(128), 0, stream,
                       rw, readout_w, readout_b, T);
    hipLaunchKernelGGL(qcr_rows, dim3((nb + 255) / 256), dim3(256), 0, stream,
                       x_short, x_long, conv_s_w, conv_s_b, lin_s_w, lin_s_b,
                       conv_l_w, conv_l_b, lin_l_w, lin_l_b, T, out, nb);
}